// Round 9
// baseline (1035.841 us; speedup 1.0000x reference)
//
#include <hip/hip_runtime.h>
#include <math.h>
#include <float.h>

#define BN_EPS 1e-5f
#define GB 512           // grid blocks; 2/CU on 256 CUs, all co-resident
#define ACAP 8192        // arena ints per 256-node bucket (= 32 KB = v window)
#define PMAX 3328        // max edges per partition chunk (E/GB = 3125)

typedef short s16x8 __attribute__((ext_vector_type(8)));
typedef float f32x4 __attribute__((ext_vector_type(4)));

__device__ __forceinline__ unsigned short f2bf(float f) {
    unsigned u = __float_as_uint(f);
    u += 0x7FFFu + ((u >> 16) & 1u);          // round-to-nearest-even
    return (unsigned short)(u >> 16);
}
__device__ __forceinline__ float bf2f(unsigned short b) {
    return __uint_as_float(((unsigned)b) << 16);
}

union SMem {
    struct {
        int hist[512], lstart[512], goff[512], cur[512];
        int sorted[PMAX];
        unsigned short sbkt[PMAX];
    } p2;                                      // ~28 KB
    float acc[256 * 64];                       // 64 KB (gather tile)
    unsigned short tile[4][16][72];            // mlp LDS round-trip
    struct { float red[4]; float ps[256]; } p5;
};

// Device-scope grid barrier.  bar zeroed by memset node each launch; targets
// are cumulative k*GB.  Release/acquire via __threadfence (wbl2/inv on gfx950).
__device__ __forceinline__ void gbar(unsigned* bar, unsigned target) {
    __syncthreads();
    if (threadIdx.x == 0) {
        __threadfence();
        atomicAdd(bar, 1u);
        int guard = 0;
        while (atomicAdd(bar, 0u) < target) {
            __builtin_amdgcn_s_sleep(8);
            if (++guard > (1 << 22)) break;   // bounded spin: fail loud, not hung
        }
        __threadfence();
    }
    __syncthreads();
}

__global__ __launch_bounds__(256, 2) void mega(
    const float* __restrict__ x,
    const int* __restrict__ src, const int* __restrict__ dst,
    const int* __restrict__ batch,
    const float* __restrict__ W1, const float* __restrict__ b1,
    const float* __restrict__ W2, const float* __restrict__ b2,
    const float* __restrict__ Wg, const float* __restrict__ bg,
    const float* __restrict__ bng, const float* __restrict__ bnb,
    const float* __restrict__ bnm, const float* __restrict__ bnv,
    const float* __restrict__ Wl, const float* __restrict__ bl,
    float* __restrict__ out,
    unsigned short* __restrict__ vbuf,      // bf16 v; aliases packed2 arenas
    unsigned short* __restrict__ hxb,       // xb (P1-P3), then h (P4-P5)
    float* __restrict__ gate,
    int* __restrict__ bcur0, unsigned* __restrict__ bar,
    unsigned short* __restrict__ w1t, unsigned short* __restrict__ w2t,
    int N, int E, int G, int NBUCK, int PBLK)
{
    __shared__ SMem sm;
    int tid  = threadIdx.x;
    int lane = tid & 63;
    int wave = tid >> 6;
    int blk  = blockIdx.x;
    int* packed2 = (int*)vbuf;

    // ---------------- P1: prep (xb cvt, weight transpose, zero bcur0) -----
    {
        int n4 = N * 16;
        for (int i = blk * 256 + tid; i < n4; i += GB * 256) {
            float4 f = *(const float4*)(x + (size_t)i * 4);
            ushort4 o;
            o.x = f2bf(f.x); o.y = f2bf(f.y); o.z = f2bf(f.z); o.w = f2bf(f.w);
            *(ushort4*)(hxb + (size_t)i * 4) = o;
        }
        if (blk == 0)
            for (int idx = tid; idx < 4096; idx += 256)
                w1t[idx] = f2bf(W1[(idx & 63) * 64 + (idx >> 6)]);
        if (blk == 1)
            for (int idx = tid; idx < 4096; idx += 256)
                w2t[idx] = f2bf(W2[(idx & 63) * 64 + (idx >> 6)]);
        if (blk == 2) { bcur0[tid] = 0; bcur0[tid + 256] = 0; }
    }
    gbar(bar, 1u * GB);

    // ---------------- P2: partition edges into per-bucket arenas ----------
    {
        int e0  = blk * PBLK;
        int cnt = E - e0; if (cnt > PBLK) cnt = PBLK; if (cnt < 0) cnt = 0;

        sm.p2.hist[tid] = 0; sm.p2.hist[tid + 256] = 0;
        __syncthreads();
        for (int i = tid; i < cnt; i += 256)
            atomicAdd(&sm.p2.hist[dst[e0 + i] >> 8], 1);
        __syncthreads();
        if (tid < 64) {
            int carry = 0;
            for (int c = 0; c < 8; ++c) {
                int v = sm.p2.hist[c * 64 + lane];
                int xv = v;
                #pragma unroll
                for (int d = 1; d < 64; d <<= 1) {
                    int t = __shfl_up(xv, d); if (lane >= d) xv += t;
                }
                sm.p2.lstart[c * 64 + lane] = xv - v + carry;
                carry += __shfl(xv, 63);
            }
        }
        __syncthreads();
        sm.p2.cur[tid] = sm.p2.lstart[tid];
        sm.p2.cur[tid + 256] = sm.p2.lstart[tid + 256];
        for (int b = tid; b < 512; b += 256)
            if (b < NBUCK && sm.p2.hist[b] > 0)
                sm.p2.goff[b] = atomicAdd(&bcur0[b], sm.p2.hist[b]);
        __syncthreads();
        for (int i = tid; i < cnt; i += 256) {
            int d = dst[e0 + i];
            int s = src[e0 + i];
            int b = d >> 8;
            int p = atomicAdd(&sm.p2.cur[b], 1);
            sm.p2.sorted[p] = ((d & 255) << 17) | s;
            sm.p2.sbkt[p] = (unsigned short)b;
        }
        __syncthreads();
        for (int i = tid; i < cnt; i += 256) {
            int b = sm.p2.sbkt[i];
            packed2[(size_t)b * ACAP + sm.p2.goff[b] + (i - sm.p2.lstart[b])]
                = sm.p2.sorted[i];
        }
    }
    gbar(bar, 2u * GB);

    // ---------------- P3: bucket gather (LDS fp32 accumulate) -------------
    if (blk < NBUCK) {
        int b = blk;
        int node0 = b * 256;
        int nn = N - node0; if (nn > 256) nn = 256;

        // init acc = self term (xb rows), coalesced
        for (int idx = tid; idx < 256 * 64; idx += 256) {
            int row = idx >> 6, f = idx & 63;
            sm.acc[idx] = (row < nn)
                ? bf2f(hxb[(size_t)(node0 + row) * 64 + f]) : 0.f;
        }
        __syncthreads();

        int ecnt = bcur0[b];
        const int* arena = packed2 + (size_t)b * ACAP;

        for (int base = wave * 64; base < ecnt; base += 256) {
            int idx2 = base + lane;
            int pk = (idx2 < ecnt) ? arena[idx2] : 0;
            int cnt64 = ecnt - base; if (cnt64 > 64) cnt64 = 64;
            int j = 0;
            for (; j + 16 <= cnt64; j += 16) {
                float t[16]; int dl[16];
                #pragma unroll
                for (int q = 0; q < 16; ++q) {
                    int pv = __builtin_amdgcn_readlane(pk, j + q);
                    dl[q] = pv >> 17;
                    t[q] = bf2f(hxb[(size_t)(pv & 0x1FFFF) * 64 + lane]);
                }
                #pragma unroll
                for (int q = 0; q < 16; ++q)
                    atomicAdd(&sm.acc[dl[q] * 64 + lane], t[q]);
            }
            for (; j < cnt64; ++j) {
                int pv = __builtin_amdgcn_readlane(pk, j);
                atomicAdd(&sm.acc[(pv >> 17) * 64 + lane],
                          bf2f(hxb[(size_t)(pv & 0x1FFFF) * 64 + lane]));
            }
        }
        __syncthreads();   // all arena reads done before overwriting window

        for (int idx = tid; idx < nn * 32; idx += 256) {
            int row = idx >> 5, p = idx & 31;
            unsigned lo = f2bf(sm.acc[row * 64 + 2 * p]);
            unsigned hi = f2bf(sm.acc[row * 64 + 2 * p + 1]);
            ((unsigned*)vbuf)[(size_t)(node0 + row) * 32 + p] = lo | (hi << 16);
        }
    }
    gbar(bar, 3u * GB);

    // ---------------- P4: MFMA MLP over 64-node tiles ---------------------
    {
        int quad = lane >> 4;
        int col  = lane & 15;

        s16x8 w1f[4][2], w2f[4][2];
        #pragma unroll
        for (int nt = 0; nt < 4; ++nt)
            #pragma unroll
            for (int kh = 0; kh < 2; ++kh) {
                int off = (nt * 16 + col) * 64 + kh * 32 + quad * 8;
                w1f[nt][kh] = *(const s16x8*)(w1t + off);
                w2f[nt][kh] = *(const s16x8*)(w2t + off);
            }
        float b1v[4], b2v[4], wgv[4];
        #pragma unroll
        for (int nt = 0; nt < 4; ++nt) {
            b1v[nt] = b1[nt * 16 + col];
            b2v[nt] = b2[nt * 16 + col];
            wgv[nt] = Wg[nt * 16 + col];
        }
        float bgv = bg[0];
        int NT = (N + 63) >> 6;

        for (int t = blk; t < NT; t += GB) {
            int base = t * 64 + wave * 16;
            const unsigned short* vrow = vbuf + (size_t)(base + col) * 64;
            s16x8 a0 = *(const s16x8*)(vrow + quad * 8);
            s16x8 a1 = *(const s16x8*)(vrow + 32 + quad * 8);

            f32x4 acc1[4];
            #pragma unroll
            for (int nt = 0; nt < 4; ++nt) {
                f32x4 c = {0.f, 0.f, 0.f, 0.f};
                c = __builtin_amdgcn_mfma_f32_16x16x32_bf16(a0, w1f[nt][0], c, 0, 0, 0);
                c = __builtin_amdgcn_mfma_f32_16x16x32_bf16(a1, w1f[nt][1], c, 0, 0, 0);
                acc1[nt] = c;
            }
            #pragma unroll
            for (int nt = 0; nt < 4; ++nt)
                #pragma unroll
                for (int r = 0; r < 4; ++r) {
                    float hv = fmaxf(acc1[nt][r] + b1v[nt], 0.f);
                    sm.tile[wave][quad * 4 + r][nt * 16 + col] = f2bf(hv);
                }
            s16x8 g0 = *(const s16x8*)&sm.tile[wave][col][quad * 8];
            s16x8 g1 = *(const s16x8*)&sm.tile[wave][col][32 + quad * 8];

            f32x4 acc2[4];
            #pragma unroll
            for (int nt = 0; nt < 4; ++nt) {
                f32x4 c = {0.f, 0.f, 0.f, 0.f};
                c = __builtin_amdgcn_mfma_f32_16x16x32_bf16(g0, w2f[nt][0], c, 0, 0, 0);
                c = __builtin_amdgcn_mfma_f32_16x16x32_bf16(g1, w2f[nt][1], c, 0, 0, 0);
                acc2[nt] = c;
            }
            float gp[4] = {0.f, 0.f, 0.f, 0.f};
            #pragma unroll
            for (int nt = 0; nt < 4; ++nt)
                #pragma unroll
                for (int r = 0; r < 4; ++r) {
                    float hv = fmaxf(acc2[nt][r] + b2v[nt], 0.f);
                    hxb[(size_t)(base + quad * 4 + r) * 64 + nt * 16 + col] = f2bf(hv);
                    gp[r] = fmaf(hv, wgv[nt], gp[r]);
                }
            #pragma unroll
            for (int r = 0; r < 4; ++r) {
                float tt = gp[r];
                tt += __shfl_xor(tt, 1);
                tt += __shfl_xor(tt, 2);
                tt += __shfl_xor(tt, 4);
                tt += __shfl_xor(tt, 8);
                int node = base + quad * 4 + r;
                if (col == 0 && node < N) gate[node] = tt + bgv;
            }
        }
    }
    gbar(bar, 4u * GB);

    // ---------------- P5: pool + BN + linear + log_softmax ----------------
    for (int g = blk; g < G; g += GB) {
        int lo = 0, hi = N;
        while (lo < hi) { int mid = (lo + hi) >> 1; if (batch[mid] < g) lo = mid + 1; else hi = mid; }
        int start = lo;
        hi = N;
        while (lo < hi) { int mid = (lo + hi) >> 1; if (batch[mid] < g + 1) lo = mid + 1; else hi = mid; }
        int end = lo;

        float m = -FLT_MAX;
        for (int i = start + tid; i < end; i += 256) m = fmaxf(m, gate[i]);
        #pragma unroll
        for (int off = 32; off; off >>= 1) m = fmaxf(m, __shfl_xor(m, off));
        if (lane == 0) sm.p5.red[wave] = m;
        __syncthreads();
        m = fmaxf(fmaxf(sm.p5.red[0], sm.p5.red[1]),
                  fmaxf(sm.p5.red[2], sm.p5.red[3]));
        __syncthreads();

        float s = 0.f;
        for (int i = start + tid; i < end; i += 256) s += expf(gate[i] - m);
        #pragma unroll
        for (int off = 32; off; off >>= 1) s += __shfl_xor(s, off);
        if (lane == 0) sm.p5.red[wave] = s;
        __syncthreads();
        s = sm.p5.red[0] + sm.p5.red[1] + sm.p5.red[2] + sm.p5.red[3];

        float a0 = 0.f, a1 = 0.f, a2 = 0.f, a3 = 0.f;
        int i = start + wave;
        for (; i + 12 < end; i += 16) {
            float e0 = expf(gate[i]      - m);
            float e1 = expf(gate[i + 4]  - m);
            float e2 = expf(gate[i + 8]  - m);
            float e3 = expf(gate[i + 12] - m);
            float t0 = bf2f(hxb[(size_t)(i)      * 64 + lane]);
            float t1 = bf2f(hxb[(size_t)(i + 4)  * 64 + lane]);
            float t2 = bf2f(hxb[(size_t)(i + 8)  * 64 + lane]);
            float t3 = bf2f(hxb[(size_t)(i + 12) * 64 + lane]);
            a0 = fmaf(e0, t0, a0); a1 = fmaf(e1, t1, a1);
            a2 = fmaf(e2, t2, a2); a3 = fmaf(e3, t3, a3);
        }
        for (; i < end; i += 4) {
            float e = expf(gate[i] - m);
            a0 = fmaf(e, bf2f(hxb[(size_t)i * 64 + lane]), a0);
        }
        sm.p5.ps[wave * 64 + lane] = (a0 + a1) + (a2 + a3);
        __syncthreads();

        if (wave == 0) {
            float p = sm.p5.ps[lane] + sm.p5.ps[64 + lane]
                    + sm.p5.ps[128 + lane] + sm.p5.ps[192 + lane];
            p = (end > start) ? (p / s) : 0.f;
            float nrm = (p - bnm[lane]) / sqrtf(bnv[lane] + BN_EPS) * bng[lane] + bnb[lane];
            float l0 = nrm * Wl[lane * 2 + 0];
            float l1 = nrm * Wl[lane * 2 + 1];
            #pragma unroll
            for (int off = 32; off; off >>= 1) {
                l0 += __shfl_xor(l0, off);
                l1 += __shfl_xor(l1, off);
            }
            if (lane == 0) {
                l0 += bl[0];
                l1 += bl[1];
                float mx = fmaxf(l0, l1);
                float lse = mx + logf(expf(l0 - mx) + expf(l1 - mx));
                out[g * 2 + 0] = l0 - lse;
                out[g * 2 + 1] = l1 - lse;
            }
        }
        __syncthreads();
    }
}

// ---------------------------------------------------------------------------
extern "C" void kernel_launch(void* const* d_in, const int* in_sizes, int n_in,
                              void* d_out, int out_size, void* d_ws, size_t ws_size,
                              hipStream_t stream)
{
    const float* x     = (const float*)d_in[0];
    const int*   eidx  = (const int*)d_in[1];   // [2, E]: row0=src, row1=dst
    const int*   batch = (const int*)d_in[2];
    const float* W1    = (const float*)d_in[3];
    const float* b1    = (const float*)d_in[4];
    const float* W2    = (const float*)d_in[5];
    const float* b2    = (const float*)d_in[6];
    const float* Wg    = (const float*)d_in[7];
    const float* bg    = (const float*)d_in[8];
    const float* bng   = (const float*)d_in[9];
    const float* bnb   = (const float*)d_in[10];
    const float* bnm   = (const float*)d_in[11];
    const float* bnv   = (const float*)d_in[12];
    const float* Wl    = (const float*)d_in[13];
    const float* bl    = (const float*)d_in[14];
    float* out = (float*)d_out;

    int N = in_sizes[0] / 64;        // requires N < 131072 (17-bit src pack)
    int E = in_sizes[1] / 2;
    int G = out_size / 2;
    int NP = ((N + 63) / 64) * 64;
    int NBUCK = (N + 255) / 256;     // <= 512
    int PBLK = (E + GB - 1) / GB;    // <= PMAX

    char* w = (char*)d_ws;
    size_t vbytes = (size_t)NBUCK * ACAP * 4;            // >= NP*128
    unsigned short* vbuf = (unsigned short*)w;  w += vbytes;
    unsigned short* hxb  = (unsigned short*)w;  w += (size_t)NP * 64 * 2;
    float* gate  = (float*)w;                   w += ((size_t)N * 4 + 255) / 256 * 256;
    int* bcur0   = (int*)w;                     w += 512 * 4;
    unsigned* bar = (unsigned*)w;               w += 128;
    unsigned short* w1t = (unsigned short*)w;   w += 4096 * 2;
    unsigned short* w2t = (unsigned short*)w;

    const int* src = eidx;
    const int* dst = eidx + E;

    hipMemsetAsync(bar, 0, 128, stream);

    mega<<<GB, 256, 0, stream>>>(x, src, dst, batch, W1, b1, W2, b2, Wg, bg,
                                 bng, bnb, bnm, bnv, Wl, bl, out,
                                 vbuf, hxb, gate, bcur0, bar, w1t, w2t,
                                 N, E, G, NBUCK, PBLK);
}